// Round 4
// baseline (115.903 us; speedup 1.0000x reference)
//
#include <hip/hip_runtime.h>

// Damped EMA: h[t] = a*x[t] + (1-a)*h[t-1], h[-1]=0, over (B,T,D) fp32.
// Chunked along T with truncated warm-up window (r^W below fp32 noise).
// Round 4: CHUNK 32->16 (16 waves/CU), whole chunk's loads issued as one
// batch (GRP=16). Warm-up re-reads are L3 hits (x = 64 MiB << 256 MiB L3).

#define B_ 4
#define T_ 4096
#define D_ 1024
#define CHUNK 16    // timesteps per block
#define DB 256      // floats of D per block = 64 lanes * float4
#define WFIX 16     // unrolled warm-up window (r^16 = 1e-16 for r=0.1)

typedef float v4f __attribute__((ext_vector_type(4)));

__global__ __launch_bounds__(64)
void ema_scan_kernel(const float* __restrict__ x,
                     const float* __restrict__ alpha,
                     float* __restrict__ out) {
    const int lane    = threadIdx.x;            // 0..63
    const int dSplits = D_ / DB;                // 4
    const int chunk   = blockIdx.x / dSplits;   // 0..T_/CHUNK-1
    const int dseg    = blockIdx.x % dSplits;
    const int b       = blockIdx.y;
    const int d0      = dseg * DB + lane * 4;
    const int t0      = chunk * CHUNK;

    const float a = alpha[0];
    const float r = 1.0f - a;

    // Window length so truncated history < ~1e-12 relative.
    int W;
    if (!(r > 0.0f)) {
        W = 0;                       // alpha >= 1: no history matters
    } else if (r >= 1.0f) {
        W = t0;                      // alpha <= 0: need full history (exact)
    } else {
        W = (int)ceilf(28.0f / (-logf(r)));
        if (W < WFIX) W = WFIX;      // round up to the unrolled fast path
        if (W > t0)   W = t0;       // chunk 0: W=0, exact
    }

    const float* xp = x   + ((size_t)b * T_ + (size_t)(t0 - W)) * D_ + d0;
    float*       op = out + ((size_t)b * T_ + (size_t)t0) * D_ + d0;

    v4f h = (v4f)(0.0f);
    v4f xv[CHUNK > WFIX ? CHUNK : WFIX];

    // ---- warm-up (discarded outputs), all loads in flight first ----
    if (W == WFIX) {
#pragma unroll
        for (int i = 0; i < WFIX; ++i) xv[i] = *(const v4f*)(xp + (size_t)i * D_);
        xp += (size_t)WFIX * D_;
#pragma unroll
        for (int i = 0; i < WFIX; ++i) h = r * h + a * xv[i];
    } else {
        for (int i = 0; i < W; ++i) {
            v4f t = *(const v4f*)xp;
            xp += D_;
            h = r * h + a * t;
        }
    }

    // ---- main: whole chunk's loads in flight, then compute+store ----
#pragma unroll
    for (int j = 0; j < CHUNK; ++j) xv[j] = *(const v4f*)(xp + (size_t)j * D_);
#pragma unroll
    for (int j = 0; j < CHUNK; ++j) {
        h = r * h + a * xv[j];
        __builtin_nontemporal_store(h, (v4f*)(op + (size_t)j * D_));
    }
}

extern "C" void kernel_launch(void* const* d_in, const int* in_sizes, int n_in,
                              void* d_out, int out_size, void* d_ws, size_t ws_size,
                              hipStream_t stream) {
    const float* x     = (const float*)d_in[0];
    const float* alpha = (const float*)d_in[1];
    float*       out   = (float*)d_out;

    dim3 grid((T_ / CHUNK) * (D_ / DB), B_);  // 1024 x 4 = 4096 blocks
    ema_scan_kernel<<<grid, 64, 0, stream>>>(x, alpha, out);
}

// Round 5
// 112.600 us; speedup vs baseline: 1.0293x; 1.0293x over previous
//
#include <hip/hip_runtime.h>

// Damped EMA: h[t] = a*x[t] + (1-a)*h[t-1], h[-1]=0, over (B,T,D) fp32.
// Chunked along T with truncated warm-up window (r^W below tolerance).
// Round 5: CHUNK=32 (round-3 best), warm-up W 16->8 (r^8=1e-8 << 9.7e-2
// threshold; halves re-read), software-pipelined main loop (double-buffered
// groups of 8 so loads overlap the compute+store of the previous group).

#define B_ 4
#define T_ 4096
#define D_ 1024
#define CHUNK 32    // timesteps per block
#define DB 256      // floats of D per block = 64 lanes * float4
#define WFIX 8      // unrolled warm-up window (r^8 = 1e-8 for r=0.1)
#define GRP 8       // timesteps per pipelined group
#define NGRP (CHUNK / GRP)

typedef float v4f __attribute__((ext_vector_type(4)));

__global__ __launch_bounds__(64)
void ema_scan_kernel(const float* __restrict__ x,
                     const float* __restrict__ alpha,
                     float* __restrict__ out) {
    const int lane    = threadIdx.x;            // 0..63
    const int dSplits = D_ / DB;                // 4
    const int chunk   = blockIdx.x / dSplits;   // 0..T_/CHUNK-1
    const int dseg    = blockIdx.x % dSplits;
    const int b       = blockIdx.y;
    const int d0      = dseg * DB + lane * 4;
    const int t0      = chunk * CHUNK;

    const float a = alpha[0];
    const float r = 1.0f - a;

    // Window length so truncated history < ~1e-8 absolute.
    int W;
    if (!(r > 0.0f)) {
        W = 0;                       // alpha >= 1: no history matters
    } else if (r >= 1.0f) {
        W = t0;                      // alpha <= 0: need full history (exact)
    } else {
        W = (int)ceilf(18.0f / (-logf(r)));
        if (W < WFIX) W = WFIX;      // round up to the unrolled fast path
        if (W > t0)   W = t0;        // chunk 0: W=0, exact
    }

    const float* xp = x   + ((size_t)b * T_ + (size_t)(t0 - W)) * D_ + d0;
    float*       op = out + ((size_t)b * T_ + (size_t)t0) * D_ + d0;

    v4f h = (v4f)(0.0f);

    if (W == WFIX) {
        // Fast path: warm-up + group0 loads all issued before any wait.
        v4f w[WFIX];
        v4f g[2][GRP];
        const float* xm = xp + (size_t)WFIX * D_;   // start of main region
#pragma unroll
        for (int i = 0; i < WFIX; ++i) w[i] = *(const v4f*)(xp + (size_t)i * D_);
#pragma unroll
        for (int j = 0; j < GRP; ++j)  g[0][j] = *(const v4f*)(xm + (size_t)j * D_);

#pragma unroll
        for (int i = 0; i < WFIX; ++i) h = r * h + a * w[i];

#pragma unroll
        for (int gi = 0; gi < NGRP; ++gi) {
            if (gi + 1 < NGRP) {
                const float* xn = xm + (size_t)(gi + 1) * GRP * D_;
#pragma unroll
                for (int j = 0; j < GRP; ++j)
                    g[(gi + 1) & 1][j] = *(const v4f*)(xn + (size_t)j * D_);
            }
#pragma unroll
            for (int j = 0; j < GRP; ++j) {
                h = r * h + a * g[gi & 1][j];
                __builtin_nontemporal_store(
                    h, (v4f*)(op + ((size_t)gi * GRP + j) * D_));
            }
        }
    } else {
        // Generic path (chunk 0 or unusual alpha): simple serial scan.
        for (int i = 0; i < W; ++i) {
            v4f t = *(const v4f*)xp;
            xp += D_;
            h = r * h + a * t;
        }
        for (int j = 0; j < CHUNK; ++j) {
            v4f t = *(const v4f*)xp;
            xp += D_;
            h = r * h + a * t;
            __builtin_nontemporal_store(h, (v4f*)(op + (size_t)j * D_));
        }
    }
}

extern "C" void kernel_launch(void* const* d_in, const int* in_sizes, int n_in,
                              void* d_out, int out_size, void* d_ws, size_t ws_size,
                              hipStream_t stream) {
    const float* x     = (const float*)d_in[0];
    const float* alpha = (const float*)d_in[1];
    float*       out   = (float*)d_out;

    dim3 grid((T_ / CHUNK) * (D_ / DB), B_);  // 512 x 4 = 2048 blocks
    ema_scan_kernel<<<grid, 64, 0, stream>>>(x, alpha, out);
}